// Round 8
// baseline (297.169 us; speedup 1.0000x reference)
//
#include <hip/hip_runtime.h>
#include <hip/hip_bf16.h>

// MHA: B=4, S=2048, D_MODEL=1024, H=16, DK=64
// ws layout (bytes):
//   [0, 8388608)            Wt: 4 x bf16[1024][1024]  (row n, col k)  = W^T
//   [8388608, +16777216)    Q  bf16 [B][H][S][64]   (scaled by log2e/8)
//   next  +16777216         K  bf16 [B][H][S][64]
//   next  +16777216         V  bf16 [B][H][64][S]
//   next  +16777216         attn out bf16 [8192][1024]
//   next  +2097152          mask bits u64 [B][S][S/64]
// total 77,594,624 B

typedef __bf16 bf16;
typedef __bf16 bf16x4 __attribute__((ext_vector_type(4)));
typedef __bf16 bf16x8 __attribute__((ext_vector_type(8)));
typedef float f32x4 __attribute__((ext_vector_type(4)));
typedef float f32x16 __attribute__((ext_vector_type(16)));
typedef unsigned int uint;

__device__ __forceinline__ void gload_lds16(const void* g, void* l) {
  __builtin_amdgcn_global_load_lds(
      (__attribute__((address_space(1))) void*)g,
      (__attribute__((address_space(3))) void*)l, 16, 0, 0);
}

// ---------------- W transpose + bf16 convert ----------------
__global__ __launch_bounds__(256) void wt_kernel(const float* __restrict__ Wq,
                                                 const float* __restrict__ Wk,
                                                 const float* __restrict__ Wv,
                                                 const float* __restrict__ Wo,
                                                 bf16* __restrict__ wt) {
  __shared__ float tile[64][65];
  const int z = blockIdx.z;
  const float* W = (z == 0) ? Wq : (z == 1) ? Wk : (z == 2) ? Wv : Wo;
  bf16* out = wt + (size_t)z * 1048576;
  const int k0 = blockIdx.x * 64, n0 = blockIdx.y * 64;
  for (int e = threadIdx.x; e < 4096; e += 256) {
    int r = e >> 6, c = e & 63;
    tile[r][c] = W[(size_t)(k0 + r) * 1024 + n0 + c];
  }
  __syncthreads();
  for (int e = threadIdx.x; e < 4096; e += 256) {
    int r = e >> 6, c = e & 63;
    out[(size_t)(n0 + r) * 1024 + k0 + c] = (bf16)tile[c][r];
  }
}

// ---------------- mask -> bit pack (4 words per wave) ----------------
__global__ __launch_bounds__(256) void maskpack_kernel(const int* __restrict__ mask,
                                                       unsigned long long* __restrict__ bits) {
  const int lane = threadIdx.x & 63;
  const int wv = threadIdx.x >> 6;
  const int word0 = blockIdx.x * 16 + wv * 4;
#pragma unroll
  for (int m = 0; m < 4; ++m) {
    int v = mask[(size_t)(word0 + m) * 64 + lane];
    unsigned long long b = __ballot(v != 0);
    if (lane == 0) bits[word0 + m] = b;
  }
}

// ---------------- fused QKV GEMM: C[8192][1024] = A @ Wt^T + bias ----------------
// 512 thr / 8 waves share one 128x128 tile (wave grid 2x4, each wave 64x32 out).
// T14 depth-2: A(t+2) fp32 loads issued after the stage barrier, consumed 2 iters later.
// blockIdx.z picks (A, W, bias, out): z=0 -> Q (scaled log2e/8), z=1 -> K, z=2 -> V.
__global__ __launch_bounds__(512, 4) void qkv_gemm_kernel(
    const float* __restrict__ Aq, const float* __restrict__ Ak, const float* __restrict__ Av,
    const bf16* __restrict__ wt, const float* __restrict__ bqp, const float* __restrict__ bkp,
    const float* __restrict__ bvp, char* __restrict__ qbuf, char* __restrict__ kbuf,
    char* __restrict__ vbuf) {
  __shared__ alignas(16) char smem[32768];
  char* As = smem;          // [128][64] bf16, 16B-slot XOR swizzle by row&7
  char* Bs = smem + 16384;  // [128 n][64 k] bf16, same swizzle
  const int t = threadIdx.x;
  const int w = t >> 6, l = t & 63;
  const int hi = l >> 4, lo = l & 15, l7 = l & 7;
  const int wr = w >> 2, wc = w & 3;  // wave tile: rows [wr*64,+64), cols [wc*32,+32)
  const int row0 = blockIdx.x * 128;
  const int n0 = blockIdx.y * 128;
  const int z = blockIdx.z;
  const float* A = (z == 0) ? Aq : (z == 1) ? Ak : Av;
  const char* Bb = (const char*)(wt + (size_t)z * 1048576);
  const float* bias = (z == 0) ? bqp : (z == 1) ? bkp : bvp;
  char* ob = (z == 0) ? qbuf : (z == 1) ? kbuf : vbuf;

  // per-thread A-stage coords (4 quads)
  int ar[4], aq_[4];
#pragma unroll
  for (int i = 0; i < 4; ++i) {
    int qq = i * 512 + t;
    ar[i] = qq >> 4;
    aq_[i] = qq & 15;
  }
  auto loadA = [&](int kt, f32x4* dst) {
#pragma unroll
    for (int i = 0; i < 4; ++i)
      dst[i] = *(const f32x4*)(A + (size_t)(row0 + ar[i]) * 1024 + kt * 64 + aq_[i] * 4);
  };
  auto writeA = [&](const f32x4* src) {
#pragma unroll
    for (int i = 0; i < 4; ++i) {
      bf16x4 hq = {(bf16)src[i][0], (bf16)src[i][1], (bf16)src[i][2], (bf16)src[i][3]};
      *(bf16x4*)(As + ar[i] * 128 + ((aq_[i] * 8) ^ ((ar[i] & 7) << 4))) = hq;
    }
  };

  const f32x4 fz = {0.f, 0.f, 0.f, 0.f};
  f32x4 acc[4][2];
#pragma unroll
  for (int mi = 0; mi < 4; ++mi)
#pragma unroll
    for (int ni = 0; ni < 2; ++ni) acc[mi][ni] = fz;

  f32x4 aA[4], aB[4];
  loadA(0, aA);
  loadA(1, aB);

#pragma unroll 1
  for (int kt2 = 0; kt2 < 8; ++kt2) {
#pragma unroll
    for (int half = 0; half < 2; ++half) {
      const int kt = kt2 * 2 + half;
      writeA(half == 0 ? aA : aB);
#pragma unroll
      for (int i = 0; i < 2; ++i) {
        int c = i * 512 + t;
        int r = c >> 3, s = c & 7;
        gload_lds16(Bb + (size_t)(n0 + r) * 2048 + kt * 128 + ((s ^ (r & 7)) * 16),
                    Bs + (i * 512 + w * 64) * 16);
      }
      __syncthreads();
      {
        int ktn = kt + 2 > 15 ? 15 : kt + 2;  // clamped redundant last loads
        loadA(ktn, half == 0 ? aA : aB);
      }
#pragma unroll
      for (int kk = 0; kk < 2; ++kk) {
        bf16x8 af[4], bfr[2];
#pragma unroll
        for (int mi = 0; mi < 4; ++mi)
          af[mi] = *(const bf16x8*)(As + (wr * 64 + mi * 16 + lo) * 128 +
                                    ((kk * 64 + hi * 16) ^ (l7 << 4)));
#pragma unroll
        for (int ni = 0; ni < 2; ++ni)
          bfr[ni] = *(const bf16x8*)(Bs + (wc * 32 + ni * 16 + lo) * 128 +
                                     ((kk * 64 + hi * 16) ^ (l7 << 4)));
#pragma unroll
        for (int mi = 0; mi < 4; ++mi)
#pragma unroll
          for (int ni = 0; ni < 2; ++ni)
            acc[mi][ni] =
                __builtin_amdgcn_mfma_f32_16x16x32_bf16(af[mi], bfr[ni], acc[mi][ni], 0, 0, 0);
      }
      __syncthreads();
    }
  }

  const float scale = (z == 0) ? 0.18033688011112042f : 1.0f;  // (1/8)*log2(e) for Q
#pragma unroll
  for (int mi = 0; mi < 4; ++mi)
#pragma unroll
    for (int ni = 0; ni < 2; ++ni) {
      int gcol = n0 + wc * 32 + ni * 16 + lo;
      float bv = bias[gcol];
#pragma unroll
      for (int j = 0; j < 4; ++j) {
        int grow = row0 + wr * 64 + mi * 16 + hi * 4 + j;
        float v = (acc[mi][ni][j] + bv) * scale;
        int b = grow >> 11, si = grow & 2047, hh = gcol >> 6, d = gcol & 63;
        if (z < 2) {
          ((bf16*)ob)[((((size_t)b * 16 + hh) * 2048 + si) << 6) + d] = (bf16)v;
        } else {
          ((bf16*)ob)[((((size_t)b * 16 + hh) * 64 + d) << 11) + si] = (bf16)v;
        }
      }
    }
}

// ---------------- final GEMM: out[8192][1024] = attn(bf16) @ Wo^T + bo (fp32) --------
// 512 thr / 8 waves share one 128x128 tile (wave grid 2x4, each wave 64x32 out).
__global__ __launch_bounds__(512) void gemm3_kernel(const char* __restrict__ Aptr,
                                                    const bf16* __restrict__ Bt,
                                                    const float* __restrict__ bias,
                                                    float* __restrict__ Out) {
  __shared__ alignas(16) char smem[32768];
  char* As = smem;
  char* Bs = smem + 16384;
  const int t = threadIdx.x;
  const int w = t >> 6, l = t & 63;
  const int hi = l >> 4, lo = l & 15, l7 = l & 7;
  const int wr = w >> 2, wc = w & 3;
  const int row0 = blockIdx.x * 128;
  const int n0 = blockIdx.y * 128;

  const f32x4 fz = {0.f, 0.f, 0.f, 0.f};
  f32x4 acc[4][2];
#pragma unroll
  for (int mi = 0; mi < 4; ++mi)
#pragma unroll
    for (int ni = 0; ni < 2; ++ni) acc[mi][ni] = fz;

  for (int kt = 0; kt < 16; ++kt) {
#pragma unroll
    for (int i = 0; i < 2; ++i) {
      int c = i * 512 + t;
      int r = c >> 3, s = c & 7;
      gload_lds16(Aptr + (size_t)(row0 + r) * 2048 + kt * 128 + ((s ^ (r & 7)) * 16),
                  As + (i * 512 + w * 64) * 16);
      gload_lds16((const char*)Bt + (size_t)(n0 + r) * 2048 + kt * 128 + ((s ^ (r & 7)) * 16),
                  Bs + (i * 512 + w * 64) * 16);
    }
    __syncthreads();
#pragma unroll
    for (int kk = 0; kk < 2; ++kk) {
      bf16x8 af[4], bfr[2];
#pragma unroll
      for (int mi = 0; mi < 4; ++mi)
        af[mi] = *(const bf16x8*)(As + (wr * 64 + mi * 16 + lo) * 128 +
                                  ((kk * 64 + hi * 16) ^ (l7 << 4)));
#pragma unroll
      for (int ni = 0; ni < 2; ++ni)
        bfr[ni] = *(const bf16x8*)(Bs + (wc * 32 + ni * 16 + lo) * 128 +
                                   ((kk * 64 + hi * 16) ^ (l7 << 4)));
#pragma unroll
      for (int mi = 0; mi < 4; ++mi)
#pragma unroll
        for (int ni = 0; ni < 2; ++ni)
          acc[mi][ni] =
              __builtin_amdgcn_mfma_f32_16x16x32_bf16(af[mi], bfr[ni], acc[mi][ni], 0, 0, 0);
    }
    __syncthreads();
  }

#pragma unroll
  for (int mi = 0; mi < 4; ++mi)
#pragma unroll
    for (int ni = 0; ni < 2; ++ni) {
      int gcol = n0 + wc * 32 + ni * 16 + lo;
      float bv = bias[gcol];
#pragma unroll
      for (int j = 0; j < 4; ++j) {
        int grow = row0 + wr * 64 + mi * 16 + hi * 4 + j;
        Out[(size_t)grow * 1024 + gcol] = acc[mi][ni][j] + bv;
      }
    }
}

// ---------------- flash attention (32x32 MFMA, in-reg softmax, T14 async staging) ----
// grid (B*H=64, S/256=8), 512 thr (8 waves share one 32KB K/V tile).
// T14: K/V tile t held in regs; per iter: ds_write(t) -> barrier -> issue loads(t+1)
// -> compute (loads complete under ~2200cyc compute) -> barrier.  Single buffer,
// 2 barriers/iter (replay-proven structure); loads are linear/coalesced, swizzle on
// the ds_write dest (same involution as before -> identical LDS image).
__global__ __launch_bounds__(512, 4) void attn_kernel(const char* __restrict__ qb,
                                                      const char* __restrict__ kb,
                                                      const char* __restrict__ vb,
                                                      const unsigned long long* __restrict__ mbits,
                                                      bf16* __restrict__ out) {
  __shared__ alignas(16) char smem[32768];
  // [0,16384): Ks [128 kj][8 slots x16B], slot ^= row&7
  // [16384,32768): Vs [64 d][16 slots x16B], slot ^= row&7
  const int t = threadIdx.x;
  const int w = t >> 6, l = t & 63;
  const int q31 = l & 31, hi = l >> 5;
  const int bh = blockIdx.x, b = bh >> 4, h = bh & 15;
  const int q0 = blockIdx.y * 256;
  const int qrow = q0 + w * 32 + q31;

  // staging coords (2 K rows + 2 V rows per thread)
  int kr[2], ks[2], vr[2], vs[2];
#pragma unroll
  for (int i = 0; i < 2; ++i) {
    int c = i * 512 + t;
    kr[i] = c >> 3;
    ks[i] = c & 7;
    vr[i] = c >> 4;
    vs[i] = c & 15;
  }
  auto loadKV = [&](int kt2, bf16x8* kreg, bf16x8* vreg) {
#pragma unroll
    for (int i = 0; i < 2; ++i) {
      kreg[i] = *(const bf16x8*)(kb + (size_t)(bh * 2048 + kt2 * 128 + kr[i]) * 128 + ks[i] * 16);
      vreg[i] = *(const bf16x8*)(vb + (size_t)(bh * 64 + vr[i]) * 4096 + kt2 * 256 + vs[i] * 16);
    }
  };
  auto writeKV = [&](const bf16x8* kreg, const bf16x8* vreg) {
#pragma unroll
    for (int i = 0; i < 2; ++i) {
      *(bf16x8*)(smem + kr[i] * 128 + ((ks[i] ^ (kr[i] & 7)) * 16)) = kreg[i];
      *(bf16x8*)(smem + 16384 + vr[i] * 256 + ((vs[i] ^ (vr[i] & 7)) * 16)) = vreg[i];
    }
  };

  // Q fragments (B-operand of 32x32x16): col=qi=q31, k = kc*16 + hi*8 + e
  bf16x8 qf[4];
#pragma unroll
  for (int kc = 0; kc < 4; ++kc)
    qf[kc] = *(const bf16x8*)(qb + (size_t)(bh * 2048 + qrow) * 128 + kc * 32 + hi * 16);

  const f32x16 fz16 = {0.f, 0.f, 0.f, 0.f, 0.f, 0.f, 0.f, 0.f,
                       0.f, 0.f, 0.f, 0.f, 0.f, 0.f, 0.f, 0.f};
  f32x16 o[2];  // o[db]: O^T[d = db*32+(r&3)+8*(r>>2)+4*hi][qi=q31]
  o[0] = fz16;
  o[1] = fz16;
  float mreg = -3e38f, ls = 0.f;
  const unsigned long long* mrow = mbits + (size_t)(b * 2048 + qrow) * 32;

  bf16x8 kreg[2], vreg[2];
  loadKV(0, kreg, vreg);

#pragma unroll 1
  for (int kt2 = 0; kt2 < 16; ++kt2) {
    writeKV(kreg, vreg);
    unsigned long long mw01[2] = {mrow[kt2 * 2], mrow[kt2 * 2 + 1]};
    __syncthreads();
    // issue next tile's loads; they complete under the compute phase
    loadKV(kt2 + 1 > 15 ? 15 : kt2 + 1, kreg, vreg);

#pragma unroll
    for (int h2 = 0; h2 < 2; ++h2) {
      const unsigned long long mw = mw01[h2];

      // QK^T: sc[n] = D[kj = n*32 + crow(r,hi)][qi]
      f32x16 sc[2];
      sc[0] = fz16;
      sc[1] = fz16;
      __builtin_amdgcn_s_setprio(1);
#pragma unroll
      for (int kc = 0; kc < 4; ++kc) {
        bf16x8 kf0 = *(const bf16x8*)(smem + (h2 * 64 + q31) * 128 +
                                      (((kc * 2 + hi) ^ (q31 & 7)) * 16));
        bf16x8 kf1 = *(const bf16x8*)(smem + (h2 * 64 + 32 + q31) * 128 +
                                      (((kc * 2 + hi) ^ (q31 & 7)) * 16));
        sc[0] = __builtin_amdgcn_mfma_f32_32x32x16_bf16(kf0, qf[kc], sc[0], 0, 0, 0);
        sc[1] = __builtin_amdgcn_mfma_f32_32x32x16_bf16(kf1, qf[kc], sc[1], 0, 0, 0);
      }
      __builtin_amdgcn_s_setprio(0);

      // mask in place + row max (scores already in log2 domain)
      float tm = -3e38f;
#pragma unroll
      for (int n = 0; n < 2; ++n) {
        uint m32 = (uint)(mw >> (n * 32 + 4 * hi));
#pragma unroll
        for (int r = 0; r < 16; ++r) {
          const int bi = (r & 3) + 8 * (r >> 2);
          sc[n][r] = ((m32 >> bi) & 1u) ? sc[n][r] : -1e9f;
        }
#pragma unroll
        for (int r = 0; r < 16; r += 2) tm = fmaxf(fmaxf(tm, sc[n][r]), sc[n][r + 1]);
      }
      tm = fmaxf(tm, __shfl_xor(tm, 32));

      // defer-max (T13, THR=4): rescale only when tile max grows past mreg+4
      if (!__all(tm - mreg <= 4.f)) {
        float mn = fmaxf(mreg, tm);
        float scal = __builtin_amdgcn_exp2f(mreg - mn);
        ls *= scal;
        o[0] *= scal;
        o[1] *= scal;
        mreg = mn;
      }

      // p = exp2(sc - mreg); pack pairs to bf16x2 words
      uint wpk[2][8];
#pragma unroll
      for (int n = 0; n < 2; ++n)
#pragma unroll
        for (int r2 = 0; r2 < 8; ++r2) {
          float p0 = __builtin_amdgcn_exp2f(sc[n][2 * r2] - mreg);
          float p1 = __builtin_amdgcn_exp2f(sc[n][2 * r2 + 1] - mreg);
          ls += p0 + p1;
          uint pk;
          asm("v_cvt_pk_bf16_f32 %0, %1, %2" : "=v"(pk) : "v"(p0), "v"(p1));
          wpk[n][r2] = pk;
        }

      // build P fragments via permlane32_swap and run PV
      __builtin_amdgcn_s_setprio(1);
#pragma unroll
      for (int n = 0; n < 2; ++n)
#pragma unroll
        for (int c2 = 0; c2 < 2; ++c2) {
          uint a0 = wpk[n][4 * c2], b0 = wpk[n][4 * c2 + 2];
          uint a1 = wpk[n][4 * c2 + 1], b1 = wpk[n][4 * c2 + 3];
          asm("v_permlane32_swap_b32 %0, %1" : "+v"(a0), "+v"(b0));
          asm("v_permlane32_swap_b32 %0, %1" : "+v"(a1), "+v"(b1));
          union {
            uint u[4];
            bf16x8 v;
          } pf;
          pf.u[0] = a0;
          pf.u[1] = a1;
          pf.u[2] = b0;
          pf.u[3] = b1;
          const int c = n * 2 + c2;  // kj chunk: kj = c*16 + hi*8 + e
          const int slot = (h2 * 8 + c * 2 + hi);
          bf16x8 vf0 = *(const bf16x8*)(smem + 16384 + q31 * 256 +
                                        ((slot ^ (q31 & 7)) * 16));
          bf16x8 vf1 = *(const bf16x8*)(smem + 16384 + (32 + q31) * 256 +
                                        ((slot ^ (q31 & 7)) * 16));
          o[0] = __builtin_amdgcn_mfma_f32_32x32x16_bf16(vf0, pf.v, o[0], 0, 0, 0);
          o[1] = __builtin_amdgcn_mfma_f32_32x32x16_bf16(vf1, pf.v, o[1], 0, 0, 0);
        }
      __builtin_amdgcn_s_setprio(0);
    }
    __syncthreads();
  }

  // epilogue: both hi-halves hold partial ls; combine once
  ls += __shfl_xor(ls, 32);
  float inv = 1.f / ls;
  size_t rbase = (size_t)((b << 11) + qrow) * 1024 + h * 64;
#pragma unroll
  for (int db = 0; db < 2; ++db)
#pragma unroll
    for (int g = 0; g < 4; ++g) {
      bf16x4 hv = {(bf16)(o[db][4 * g] * inv), (bf16)(o[db][4 * g + 1] * inv),
                   (bf16)(o[db][4 * g + 2] * inv), (bf16)(o[db][4 * g + 3] * inv)};
      *(bf16x4*)(out + rbase + db * 32 + 8 * g + 4 * hi) = hv;
    }
}

extern "C" void kernel_launch(void* const* d_in, const int* in_sizes, int n_in,
                              void* d_out, int out_size, void* d_ws, size_t ws_size,
                              hipStream_t stream) {
  const float* query = (const float*)d_in[0];
  const float* key_ = (const float*)d_in[1];
  const float* value = (const float*)d_in[2];
  const int* mask = (const int*)d_in[3];
  const float* Wq = (const float*)d_in[4];
  const float* bq = (const float*)d_in[5];
  const float* Wk = (const float*)d_in[6];
  const float* bk = (const float*)d_in[7];
  const float* Wv = (const float*)d_in[8];
  const float* bv = (const float*)d_in[9];
  const float* Wo = (const float*)d_in[10];
  const float* bo = (const float*)d_in[11];

  char* ws = (char*)d_ws;
  bf16* wt = (bf16*)ws;                      // 4 x 1M bf16
  char* qbuf = ws + 8388608;
  char* kbuf = qbuf + 16777216;
  char* vbuf = kbuf + 16777216;
  char* abuf = vbuf + 16777216;
  unsigned long long* mbits = (unsigned long long*)(abuf + 16777216);

  wt_kernel<<<dim3(16, 16, 4), 256, 0, stream>>>(Wq, Wk, Wv, Wo, wt);
  maskpack_kernel<<<16384, 256, 0, stream>>>(mask, mbits);
  qkv_gemm_kernel<<<dim3(64, 8, 3), 512, 0, stream>>>(query, key_, value, wt, bq, bk, bv,
                                                      qbuf, kbuf, vbuf);
  attn_kernel<<<dim3(64, 8), 512, 0, stream>>>(qbuf, kbuf, vbuf, mbits, (bf16*)abuf);
  gemm3_kernel<<<dim3(64, 8), 512, 0, stream>>>(abuf, wt + 3145728, bo, (float*)d_out);
}

// Round 9
// 269.673 us; speedup vs baseline: 1.1020x; 1.1020x over previous
//
#include <hip/hip_runtime.h>
#include <hip/hip_bf16.h>

// MHA: B=4, S=2048, D_MODEL=1024, H=16, DK=64
// ws layout (bytes):
//   [0, 8388608)            Wt: 4 x bf16[1024][1024]  (row n, col k)  = W^T
//   [8388608, +16777216)    Q  bf16 [B][H][S][64]   (scaled by log2e/8)
//   next  +16777216         K  bf16 [B][H][S][64]
//   next  +16777216         V  bf16 [B][H][64][S]
//   next  +16777216         attn out bf16 [8192][1024]
//   next  +2097152          mask bits u64 [B][S][S/64]
// total 77,594,624 B

typedef __bf16 bf16;
typedef __bf16 bf16x4 __attribute__((ext_vector_type(4)));
typedef __bf16 bf16x8 __attribute__((ext_vector_type(8)));
typedef float f32x4 __attribute__((ext_vector_type(4)));
typedef float f32x16 __attribute__((ext_vector_type(16)));
typedef unsigned int uint;

__device__ __forceinline__ void gload_lds16(const void* g, void* l) {
  __builtin_amdgcn_global_load_lds(
      (__attribute__((address_space(1))) void*)g,
      (__attribute__((address_space(3))) void*)l, 16, 0, 0);
}

// ---------------- W transpose + bf16 convert ----------------
__global__ __launch_bounds__(256) void wt_kernel(const float* __restrict__ Wq,
                                                 const float* __restrict__ Wk,
                                                 const float* __restrict__ Wv,
                                                 const float* __restrict__ Wo,
                                                 bf16* __restrict__ wt) {
  __shared__ float tile[64][65];
  const int z = blockIdx.z;
  const float* W = (z == 0) ? Wq : (z == 1) ? Wk : (z == 2) ? Wv : Wo;
  bf16* out = wt + (size_t)z * 1048576;
  const int k0 = blockIdx.x * 64, n0 = blockIdx.y * 64;
  for (int e = threadIdx.x; e < 4096; e += 256) {
    int r = e >> 6, c = e & 63;
    tile[r][c] = W[(size_t)(k0 + r) * 1024 + n0 + c];
  }
  __syncthreads();
  for (int e = threadIdx.x; e < 4096; e += 256) {
    int r = e >> 6, c = e & 63;
    out[(size_t)(n0 + r) * 1024 + k0 + c] = (bf16)tile[c][r];
  }
}

// ---------------- mask -> bit pack (4 words per wave) ----------------
__global__ __launch_bounds__(256) void maskpack_kernel(const int* __restrict__ mask,
                                                       unsigned long long* __restrict__ bits) {
  const int lane = threadIdx.x & 63;
  const int wv = threadIdx.x >> 6;
  const int word0 = blockIdx.x * 16 + wv * 4;
#pragma unroll
  for (int m = 0; m < 4; ++m) {
    int v = mask[(size_t)(word0 + m) * 64 + lane];
    unsigned long long b = __ballot(v != 0);
    if (lane == 0) bits[word0 + m] = b;
  }
}

// ---------------- fused QKV GEMM: C[8192][1024] = A @ Wt^T + bias ----------------
// 512 thr / 8 waves share one 128x128 tile (wave grid 2x4, each wave 64x32 out).
// blockIdx.z picks (A, W, bias, out): z=0 -> Q (scaled log2e/8), z=1 -> K, z=2 -> V.
// Q,K out bf16 [B][H][S][64]; V out bf16 [B][H][64][S].  (r7 replay-proven form)
__global__ __launch_bounds__(512) void qkv_gemm_kernel(
    const float* __restrict__ Aq, const float* __restrict__ Ak, const float* __restrict__ Av,
    const bf16* __restrict__ wt, const float* __restrict__ bqp, const float* __restrict__ bkp,
    const float* __restrict__ bvp, char* __restrict__ qbuf, char* __restrict__ kbuf,
    char* __restrict__ vbuf) {
  __shared__ alignas(16) char smem[32768];
  char* As = smem;          // [128][64] bf16, 16B-slot XOR swizzle by row&7
  char* Bs = smem + 16384;  // [128 n][64 k] bf16, same swizzle
  const int t = threadIdx.x;
  const int w = t >> 6, l = t & 63;
  const int hi = l >> 4, lo = l & 15, l7 = l & 7;
  const int wr = w >> 2, wc = w & 3;  // wave tile: rows [wr*64,+64), cols [wc*32,+32)
  const int row0 = blockIdx.x * 128;
  const int n0 = blockIdx.y * 128;
  const int z = blockIdx.z;
  const float* A = (z == 0) ? Aq : (z == 1) ? Ak : Av;
  const char* Bb = (const char*)(wt + (size_t)z * 1048576);
  const float* bias = (z == 0) ? bqp : (z == 1) ? bkp : bvp;
  char* ob = (z == 0) ? qbuf : (z == 1) ? kbuf : vbuf;

  const f32x4 fz = {0.f, 0.f, 0.f, 0.f};
  f32x4 acc[4][2];
#pragma unroll
  for (int mi = 0; mi < 4; ++mi)
#pragma unroll
    for (int ni = 0; ni < 2; ++ni) acc[mi][ni] = fz;

  for (int kt = 0; kt < 16; ++kt) {
#pragma unroll
    for (int i = 0; i < 4; ++i) {
      int qq = i * 512 + t;
      int r = qq >> 4, q = qq & 15;  // row, 4-float quad along k
      f32x4 f = *(const f32x4*)(A + (size_t)(row0 + r) * 1024 + kt * 64 + q * 4);
      bf16x4 hq = {(bf16)f[0], (bf16)f[1], (bf16)f[2], (bf16)f[3]};
      *(bf16x4*)(As + r * 128 + ((q * 8) ^ ((r & 7) << 4))) = hq;
    }
#pragma unroll
    for (int i = 0; i < 2; ++i) {
      int c = i * 512 + t;
      int r = c >> 3, s = c & 7;
      gload_lds16(Bb + (size_t)(n0 + r) * 2048 + kt * 128 + ((s ^ (r & 7)) * 16),
                  Bs + (i * 512 + w * 64) * 16);
    }
    __syncthreads();
#pragma unroll
    for (int kk = 0; kk < 2; ++kk) {
      bf16x8 af[4], bfr[2];
#pragma unroll
      for (int mi = 0; mi < 4; ++mi)
        af[mi] = *(const bf16x8*)(As + (wr * 64 + mi * 16 + lo) * 128 +
                                  ((kk * 64 + hi * 16) ^ (l7 << 4)));
#pragma unroll
      for (int ni = 0; ni < 2; ++ni)
        bfr[ni] = *(const bf16x8*)(Bs + (wc * 32 + ni * 16 + lo) * 128 +
                                   ((kk * 64 + hi * 16) ^ (l7 << 4)));
#pragma unroll
      for (int mi = 0; mi < 4; ++mi)
#pragma unroll
        for (int ni = 0; ni < 2; ++ni)
          acc[mi][ni] =
              __builtin_amdgcn_mfma_f32_16x16x32_bf16(af[mi], bfr[ni], acc[mi][ni], 0, 0, 0);
    }
    __syncthreads();
  }

  const float scale = (z == 0) ? 0.18033688011112042f : 1.0f;  // (1/8)*log2(e) for Q
#pragma unroll
  for (int mi = 0; mi < 4; ++mi)
#pragma unroll
    for (int ni = 0; ni < 2; ++ni) {
      int gcol = n0 + wc * 32 + ni * 16 + lo;
      float bv = bias[gcol];
#pragma unroll
      for (int j = 0; j < 4; ++j) {
        int grow = row0 + wr * 64 + mi * 16 + hi * 4 + j;
        float v = (acc[mi][ni][j] + bv) * scale;
        int b = grow >> 11, si = grow & 2047, hh = gcol >> 6, d = gcol & 63;
        if (z < 2) {
          ((bf16*)ob)[((((size_t)b * 16 + hh) * 2048 + si) << 6) + d] = (bf16)v;
        } else {
          ((bf16*)ob)[((((size_t)b * 16 + hh) * 64 + d) << 11) + si] = (bf16)v;
        }
      }
    }
}

// ---------------- final GEMM: out[8192][1024] = attn(bf16) @ Wo^T + bo (fp32) --------
// 512 thr / 8 waves share one 128x128 tile (wave grid 2x4, each wave 64x32 out).
__global__ __launch_bounds__(512) void gemm3_kernel(const char* __restrict__ Aptr,
                                                    const bf16* __restrict__ Bt,
                                                    const float* __restrict__ bias,
                                                    float* __restrict__ Out) {
  __shared__ alignas(16) char smem[32768];
  char* As = smem;
  char* Bs = smem + 16384;
  const int t = threadIdx.x;
  const int w = t >> 6, l = t & 63;
  const int hi = l >> 4, lo = l & 15, l7 = l & 7;
  const int wr = w >> 2, wc = w & 3;
  const int row0 = blockIdx.x * 128;
  const int n0 = blockIdx.y * 128;

  const f32x4 fz = {0.f, 0.f, 0.f, 0.f};
  f32x4 acc[4][2];
#pragma unroll
  for (int mi = 0; mi < 4; ++mi)
#pragma unroll
    for (int ni = 0; ni < 2; ++ni) acc[mi][ni] = fz;

  for (int kt = 0; kt < 16; ++kt) {
#pragma unroll
    for (int i = 0; i < 2; ++i) {
      int c = i * 512 + t;
      int r = c >> 3, s = c & 7;
      gload_lds16(Aptr + (size_t)(row0 + r) * 2048 + kt * 128 + ((s ^ (r & 7)) * 16),
                  As + (i * 512 + w * 64) * 16);
      gload_lds16((const char*)Bt + (size_t)(n0 + r) * 2048 + kt * 128 + ((s ^ (r & 7)) * 16),
                  Bs + (i * 512 + w * 64) * 16);
    }
    __syncthreads();
#pragma unroll
    for (int kk = 0; kk < 2; ++kk) {
      bf16x8 af[4], bfr[2];
#pragma unroll
      for (int mi = 0; mi < 4; ++mi)
        af[mi] = *(const bf16x8*)(As + (wr * 64 + mi * 16 + lo) * 128 +
                                  ((kk * 64 + hi * 16) ^ (l7 << 4)));
#pragma unroll
      for (int ni = 0; ni < 2; ++ni)
        bfr[ni] = *(const bf16x8*)(Bs + (wc * 32 + ni * 16 + lo) * 128 +
                                   ((kk * 64 + hi * 16) ^ (l7 << 4)));
#pragma unroll
      for (int mi = 0; mi < 4; ++mi)
#pragma unroll
        for (int ni = 0; ni < 2; ++ni)
          acc[mi][ni] =
              __builtin_amdgcn_mfma_f32_16x16x32_bf16(af[mi], bfr[ni], acc[mi][ni], 0, 0, 0);
    }
    __syncthreads();
  }

#pragma unroll
  for (int mi = 0; mi < 4; ++mi)
#pragma unroll
    for (int ni = 0; ni < 2; ++ni) {
      int gcol = n0 + wc * 32 + ni * 16 + lo;
      float bv = bias[gcol];
#pragma unroll
      for (int j = 0; j < 4; ++j) {
        int grow = row0 + wr * 64 + mi * 16 + hi * 4 + j;
        Out[(size_t)grow * 1024 + gcol] = acc[mi][ni][j] + bv;
      }
    }
}

// ---------------- flash attention (32x32 MFMA, sequential-n in-reg softmax) ----------
// grid (B*H=64, S/256=8), 512 thr (8 waves share one 32KB K/V tile), gload_lds staging
// (r7 replay-proven sync structure: stage -> barrier -> compute 2 halves -> barrier).
// Register-pressure cut: the two 32-kj sub-tiles of each 64-kj half are processed
// SEQUENTIALLY (QK -> mask/max -> rescale-check -> exp2/pack -> PV per sub-tile), so
// only one f32x16 score block + 8 pack words are live at a time (unified-RF fit ->
// 4 waves/SIMD).  Online softmax with 32-wide tiles: same math, 2x rescale checks.
__global__ __launch_bounds__(512) void attn_kernel(const char* __restrict__ qb,
                                                   const char* __restrict__ kb,
                                                   const char* __restrict__ vb,
                                                   const unsigned long long* __restrict__ mbits,
                                                   bf16* __restrict__ out) {
  __shared__ alignas(16) char smem[32768];
  // [0,16384): Ks [128 kj][8 slots x16B], slot ^= row&7
  // [16384,32768): Vs [64 d][16 slots x16B], slot ^= row&7
  const int t = threadIdx.x;
  const int w = t >> 6, l = t & 63;
  const int q31 = l & 31, hi = l >> 5;
  const int bh = blockIdx.x, b = bh >> 4, h = bh & 15;
  const int q0 = blockIdx.y * 256;
  const int qrow = q0 + w * 32 + q31;

  // Q fragments (B-operand of 32x32x16): col=qi=q31, k = kc*16 + hi*8 + e
  bf16x8 qf[4];
#pragma unroll
  for (int kc = 0; kc < 4; ++kc)
    qf[kc] = *(const bf16x8*)(qb + (size_t)(bh * 2048 + qrow) * 128 + kc * 32 + hi * 16);

  const f32x16 fz16 = {0.f, 0.f, 0.f, 0.f, 0.f, 0.f, 0.f, 0.f,
                       0.f, 0.f, 0.f, 0.f, 0.f, 0.f, 0.f, 0.f};
  f32x16 o[2];  // o[db]: O^T[d = db*32+(r&3)+8*(r>>2)+4*hi][qi=q31]
  o[0] = fz16;
  o[1] = fz16;
  float mreg = -3e38f, ls = 0.f;
  const unsigned long long* mrow = mbits + (size_t)(b * 2048 + qrow) * 32;

  for (int kt2 = 0; kt2 < 16; ++kt2) {
    // stage K[128 kj][64 d] and V^T[64 d][128 kj] (16KB each), swizzled; 2 each/thread
#pragma unroll
    for (int i = 0; i < 2; ++i) {
      int c = i * 512 + t;
      int kr = c >> 3, ks = c & 7;
      gload_lds16(kb + (size_t)(bh * 2048 + kt2 * 128 + kr) * 128 + ((ks ^ (kr & 7)) * 16),
                  smem + (i * 512 + w * 64) * 16);
      int vr = c >> 4, vs = c & 15;
      gload_lds16(vb + (size_t)(bh * 64 + vr) * 4096 + kt2 * 256 + ((vs ^ (vr & 7)) * 16),
                  smem + 16384 + (i * 512 + w * 64) * 16);
    }
    // prefetch this tile's mask words while the barrier drains the staging
    unsigned long long mw01[2] = {mrow[kt2 * 2], mrow[kt2 * 2 + 1]};
    __syncthreads();

#pragma unroll
    for (int h2 = 0; h2 < 2; ++h2) {
      const unsigned long long mw = mw01[h2];

#pragma unroll
      for (int n = 0; n < 2; ++n) {
        // QK^T sub-tile: sc = D[kj = n*32 + crow(r,hi)][qi]
        f32x16 sc = fz16;
        __builtin_amdgcn_s_setprio(1);
#pragma unroll
        for (int kc = 0; kc < 4; ++kc) {
          bf16x8 kf = *(const bf16x8*)(smem + (h2 * 64 + n * 32 + q31) * 128 +
                                       (((kc * 2 + hi) ^ (q31 & 7)) * 16));
          sc = __builtin_amdgcn_mfma_f32_32x32x16_bf16(kf, qf[kc], sc, 0, 0, 0);
        }
        __builtin_amdgcn_s_setprio(0);

        // mask in place + sub-tile max (scores already in log2 domain)
        uint m32 = (uint)(mw >> (n * 32 + 4 * hi));
        float tm = -3e38f;
#pragma unroll
        for (int r = 0; r < 16; ++r) {
          const int bi = (r & 3) + 8 * (r >> 2);
          sc[r] = ((m32 >> bi) & 1u) ? sc[r] : -1e9f;
        }
#pragma unroll
        for (int r = 0; r < 16; r += 2) tm = fmaxf(fmaxf(tm, sc[r]), sc[r + 1]);
        tm = fmaxf(tm, __shfl_xor(tm, 32));

        // defer-max (T13, THR=4): rescale only when sub-tile max grows past mreg+4
        if (!__all(tm - mreg <= 4.f)) {
          float mn = fmaxf(mreg, tm);
          float scal = __builtin_amdgcn_exp2f(mreg - mn);
          ls *= scal;
          o[0] *= scal;
          o[1] *= scal;
          mreg = mn;
        }

        // p = exp2(sc - mreg); pack pairs to bf16x2 words
        uint wpk[8];
#pragma unroll
        for (int r2 = 0; r2 < 8; ++r2) {
          float p0 = __builtin_amdgcn_exp2f(sc[2 * r2] - mreg);
          float p1 = __builtin_amdgcn_exp2f(sc[2 * r2 + 1] - mreg);
          ls += p0 + p1;
          uint pk;
          asm("v_cvt_pk_bf16_f32 %0, %1, %2" : "=v"(pk) : "v"(p0), "v"(p1));
          wpk[r2] = pk;
        }

        // build P fragments via permlane32_swap and run PV for this sub-tile's chunks
        __builtin_amdgcn_s_setprio(1);
#pragma unroll
        for (int c2 = 0; c2 < 2; ++c2) {
          uint a0 = wpk[4 * c2], b0 = wpk[4 * c2 + 2];
          uint a1 = wpk[4 * c2 + 1], b1 = wpk[4 * c2 + 3];
          asm("v_permlane32_swap_b32 %0, %1" : "+v"(a0), "+v"(b0));
          asm("v_permlane32_swap_b32 %0, %1" : "+v"(a1), "+v"(b1));
          union {
            uint u[4];
            bf16x8 v;
          } pf;
          pf.u[0] = a0;
          pf.u[1] = a1;
          pf.u[2] = b0;
          pf.u[3] = b1;
          const int c = n * 2 + c2;  // kj chunk: kj = c*16 + hi*8 + e
          const int slot = (h2 * 8 + c * 2 + hi);
          bf16x8 vf0 = *(const bf16x8*)(smem + 16384 + q31 * 256 +
                                        ((slot ^ (q31 & 7)) * 16));
          bf16x8 vf1 = *(const bf16x8*)(smem + 16384 + (32 + q31) * 256 +
                                        ((slot ^ (q31 & 7)) * 16));
          o[0] = __builtin_amdgcn_mfma_f32_32x32x16_bf16(vf0, pf.v, o[0], 0, 0, 0);
          o[1] = __builtin_amdgcn_mfma_f32_32x32x16_bf16(vf1, pf.v, o[1], 0, 0, 0);
        }
        __builtin_amdgcn_s_setprio(0);
      }
    }
    __syncthreads();
  }

  // epilogue: both hi-halves hold partial ls; combine once
  ls += __shfl_xor(ls, 32);
  float inv = 1.f / ls;
  size_t rbase = (size_t)((b << 11) + qrow) * 1024 + h * 64;
#pragma unroll
  for (int db = 0; db < 2; ++db)
#pragma unroll
    for (int g = 0; g < 4; ++g) {
      bf16x4 hv = {(bf16)(o[db][4 * g] * inv), (bf16)(o[db][4 * g + 1] * inv),
                   (bf16)(o[db][4 * g + 2] * inv), (bf16)(o[db][4 * g + 3] * inv)};
      *(bf16x4*)(out + rbase + db * 32 + 8 * g + 4 * hi) = hv;
    }
}

extern "C" void kernel_launch(void* const* d_in, const int* in_sizes, int n_in,
                              void* d_out, int out_size, void* d_ws, size_t ws_size,
                              hipStream_t stream) {
  const float* query = (const float*)d_in[0];
  const float* key_ = (const float*)d_in[1];
  const float* value = (const float*)d_in[2];
  const int* mask = (const int*)d_in[3];
  const float* Wq = (const float*)d_in[4];
  const float* bq = (const float*)d_in[5];
  const float* Wk = (const float*)d_in[6];
  const float* bk = (const float*)d_in[7];
  const float* Wv = (const float*)d_in[8];
  const float* bv = (const float*)d_in[9];
  const float* Wo = (const float*)d_in[10];
  const float* bo = (const float*)d_in[11];

  char* ws = (char*)d_ws;
  bf16* wt = (bf16*)ws;                      // 4 x 1M bf16
  char* qbuf = ws + 8388608;
  char* kbuf = qbuf + 16777216;
  char* vbuf = kbuf + 16777216;
  char* abuf = vbuf + 16777216;
  unsigned long long* mbits = (unsigned long long*)(abuf + 16777216);

  wt_kernel<<<dim3(16, 16, 4), 256, 0, stream>>>(Wq, Wk, Wv, Wo, wt);
  maskpack_kernel<<<16384, 256, 0, stream>>>(mask, mbits);
  qkv_gemm_kernel<<<dim3(64, 8, 3), 512, 0, stream>>>(query, key_, value, wt, bq, bk, bv,
                                                      qbuf, kbuf, vbuf);
  attn_kernel<<<dim3(64, 8), 512, 0, stream>>>(qbuf, kbuf, vbuf, mbits, (bf16*)abuf);
  gemm3_kernel<<<dim3(64, 8), 512, 0, stream>>>(abuf, wt + 3145728, bo, (float*)d_out);
}

// Round 10
// 265.579 us; speedup vs baseline: 1.1189x; 1.0154x over previous
//
#include <hip/hip_runtime.h>
#include <hip/hip_bf16.h>

// MHA: B=4, S=2048, D_MODEL=1024, H=16, DK=64
// ws layout (bytes):
//   [0, 8388608)            Wt: 4 x bf16[1024][1024]  (row n, col k)  = W^T
//   [8388608, +16777216)    Q  bf16 [B][H][S][64]   (scaled by log2e/8)
//   next  +16777216         K  bf16 [B][H][S][64]
//   next  +16777216         V  bf16 [B][H][64][S]
//   next  +16777216         attn out bf16 [8192][1024]
//   next  +2097152          mask bits u64 [B][S][S/64]
// total 77,594,624 B

typedef __bf16 bf16;
typedef __bf16 bf16x4 __attribute__((ext_vector_type(4)));
typedef __bf16 bf16x8 __attribute__((ext_vector_type(8)));
typedef float f32x4 __attribute__((ext_vector_type(4)));
typedef float f32x16 __attribute__((ext_vector_type(16)));
typedef unsigned int uint;

__device__ __forceinline__ void gload_lds16(const void* g, void* l) {
  __builtin_amdgcn_global_load_lds(
      (__attribute__((address_space(1))) void*)g,
      (__attribute__((address_space(3))) void*)l, 16, 0, 0);
}

// ---------------- W transpose + bf16 convert ----------------
__global__ __launch_bounds__(256) void wt_kernel(const float* __restrict__ Wq,
                                                 const float* __restrict__ Wk,
                                                 const float* __restrict__ Wv,
                                                 const float* __restrict__ Wo,
                                                 bf16* __restrict__ wt) {
  __shared__ float tile[64][65];
  const int z = blockIdx.z;
  const float* W = (z == 0) ? Wq : (z == 1) ? Wk : (z == 2) ? Wv : Wo;
  bf16* out = wt + (size_t)z * 1048576;
  const int k0 = blockIdx.x * 64, n0 = blockIdx.y * 64;
  for (int e = threadIdx.x; e < 4096; e += 256) {
    int r = e >> 6, c = e & 63;
    tile[r][c] = W[(size_t)(k0 + r) * 1024 + n0 + c];
  }
  __syncthreads();
  for (int e = threadIdx.x; e < 4096; e += 256) {
    int r = e >> 6, c = e & 63;
    out[(size_t)(n0 + r) * 1024 + k0 + c] = (bf16)tile[c][r];
  }
}

// ---------------- mask -> bit pack (4 words per wave) ----------------
__global__ __launch_bounds__(256) void maskpack_kernel(const int* __restrict__ mask,
                                                       unsigned long long* __restrict__ bits) {
  const int lane = threadIdx.x & 63;
  const int wv = threadIdx.x >> 6;
  const int word0 = blockIdx.x * 16 + wv * 4;
#pragma unroll
  for (int m = 0; m < 4; ++m) {
    int v = mask[(size_t)(word0 + m) * 64 + lane];
    unsigned long long b = __ballot(v != 0);
    if (lane == 0) bits[word0 + m] = b;
  }
}

// ---------------- fused QKV GEMM (BK=128): C[8192][1024] = A @ Wt^T + bias ----------
// 512 thr / 8 waves, 128x128 tile, K-step 128 (8 iters, half the barrier drains).
// LDS 64KB: As [128 r][16 slots x16B] (swz slot^=(r&7)), Bs same.
// blockIdx.z: z=0 -> Q (scaled log2e/8), z=1 -> K, z=2 -> V.
__global__ __launch_bounds__(512) void qkv_gemm_kernel(
    const float* __restrict__ Aq, const float* __restrict__ Ak, const float* __restrict__ Av,
    const bf16* __restrict__ wt, const float* __restrict__ bqp, const float* __restrict__ bkp,
    const float* __restrict__ bvp, char* __restrict__ qbuf, char* __restrict__ kbuf,
    char* __restrict__ vbuf) {
  __shared__ alignas(16) char smem[65536];
  char* As = smem;          // [128][128] bf16, 16B-slot XOR swizzle by row&7
  char* Bs = smem + 32768;  // [128 n][128 k] bf16, same swizzle
  const int t = threadIdx.x;
  const int w = t >> 6, l = t & 63;
  const int hi = l >> 4, lo = l & 15, l7 = l & 7;
  const int wr = w >> 2, wc = w & 3;  // wave tile: rows [wr*64,+64), cols [wc*32,+32)
  const int row0 = blockIdx.x * 128;
  const int n0 = blockIdx.y * 128;
  const int z = blockIdx.z;
  const float* A = (z == 0) ? Aq : (z == 1) ? Ak : Av;
  const char* Bb = (const char*)(wt + (size_t)z * 1048576);
  const float* bias = (z == 0) ? bqp : (z == 1) ? bkp : bvp;
  char* ob = (z == 0) ? qbuf : (z == 1) ? kbuf : vbuf;

  const f32x4 fz = {0.f, 0.f, 0.f, 0.f};
  f32x4 acc[4][2];
#pragma unroll
  for (int mi = 0; mi < 4; ++mi)
#pragma unroll
    for (int ni = 0; ni < 2; ++ni) acc[mi][ni] = fz;

  for (int kt = 0; kt < 8; ++kt) {
    // A: 128x128 fp32 -> bf16, 8 quads/thread
#pragma unroll
    for (int i = 0; i < 8; ++i) {
      int qq = i * 512 + t;
      int r = qq >> 5, q = qq & 31;  // row, 4-float quad along k (32 quads/row)
      f32x4 f = *(const f32x4*)(A + (size_t)(row0 + r) * 1024 + kt * 128 + q * 4);
      bf16x4 hq = {(bf16)f[0], (bf16)f[1], (bf16)f[2], (bf16)f[3]};
      *(bf16x4*)(As + r * 256 + (((q >> 1) ^ (r & 7)) * 16 + (q & 1) * 8)) = hq;
    }
    // B: 4 gload_lds/thread (16 slots/row)
#pragma unroll
    for (int i = 0; i < 4; ++i) {
      int c = i * 512 + t;
      int r = c >> 4, s = c & 15;
      gload_lds16(Bb + (size_t)(n0 + r) * 2048 + kt * 256 + ((s ^ (r & 7)) * 16),
                  Bs + (i * 512 + w * 64) * 16);
    }
    __syncthreads();
#pragma unroll
    for (int kk = 0; kk < 4; ++kk) {
      bf16x8 af[4], bfr[2];
#pragma unroll
      for (int mi = 0; mi < 4; ++mi)
        af[mi] = *(const bf16x8*)(As + (wr * 64 + mi * 16 + lo) * 256 +
                                  ((kk * 64 + hi * 16) ^ (l7 << 4)));
#pragma unroll
      for (int ni = 0; ni < 2; ++ni)
        bfr[ni] = *(const bf16x8*)(Bs + (wc * 32 + ni * 16 + lo) * 256 +
                                   ((kk * 64 + hi * 16) ^ (l7 << 4)));
#pragma unroll
      for (int mi = 0; mi < 4; ++mi)
#pragma unroll
        for (int ni = 0; ni < 2; ++ni)
          acc[mi][ni] =
              __builtin_amdgcn_mfma_f32_16x16x32_bf16(af[mi], bfr[ni], acc[mi][ni], 0, 0, 0);
    }
    __syncthreads();
  }

  const float scale = (z == 0) ? 0.18033688011112042f : 1.0f;  // (1/8)*log2(e) for Q
#pragma unroll
  for (int mi = 0; mi < 4; ++mi)
#pragma unroll
    for (int ni = 0; ni < 2; ++ni) {
      int gcol = n0 + wc * 32 + ni * 16 + lo;
      float bv = bias[gcol];
#pragma unroll
      for (int j = 0; j < 4; ++j) {
        int grow = row0 + wr * 64 + mi * 16 + hi * 4 + j;
        float v = (acc[mi][ni][j] + bv) * scale;
        int b = grow >> 11, si = grow & 2047, hh = gcol >> 6, d = gcol & 63;
        if (z < 2) {
          ((bf16*)ob)[((((size_t)b * 16 + hh) * 2048 + si) << 6) + d] = (bf16)v;
        } else {
          ((bf16*)ob)[((((size_t)b * 16 + hh) * 64 + d) << 11) + si] = (bf16)v;
        }
      }
    }
}

// ---------------- final GEMM (BK=128): out[8192][1024] = attn(bf16) @ Wo^T + bo ------
// 512 thr / 8 waves, 128x128 tile, LDS 64KB, both operands via gload_lds.
__global__ __launch_bounds__(512) void gemm3_kernel(const char* __restrict__ Aptr,
                                                    const bf16* __restrict__ Bt,
                                                    const float* __restrict__ bias,
                                                    float* __restrict__ Out) {
  __shared__ alignas(16) char smem[65536];
  char* As = smem;
  char* Bs = smem + 32768;
  const int t = threadIdx.x;
  const int w = t >> 6, l = t & 63;
  const int hi = l >> 4, lo = l & 15, l7 = l & 7;
  const int wr = w >> 2, wc = w & 3;
  const int row0 = blockIdx.x * 128;
  const int n0 = blockIdx.y * 128;

  const f32x4 fz = {0.f, 0.f, 0.f, 0.f};
  f32x4 acc[4][2];
#pragma unroll
  for (int mi = 0; mi < 4; ++mi)
#pragma unroll
    for (int ni = 0; ni < 2; ++ni) acc[mi][ni] = fz;

  for (int kt = 0; kt < 8; ++kt) {
#pragma unroll
    for (int i = 0; i < 4; ++i) {
      int c = i * 512 + t;
      int r = c >> 4, s = c & 15;
      gload_lds16(Aptr + (size_t)(row0 + r) * 2048 + kt * 256 + ((s ^ (r & 7)) * 16),
                  As + (i * 512 + w * 64) * 16);
      gload_lds16((const char*)Bt + (size_t)(n0 + r) * 2048 + kt * 256 + ((s ^ (r & 7)) * 16),
                  Bs + (i * 512 + w * 64) * 16);
    }
    __syncthreads();
#pragma unroll
    for (int kk = 0; kk < 4; ++kk) {
      bf16x8 af[4], bfr[2];
#pragma unroll
      for (int mi = 0; mi < 4; ++mi)
        af[mi] = *(const bf16x8*)(As + (wr * 64 + mi * 16 + lo) * 256 +
                                  ((kk * 64 + hi * 16) ^ (l7 << 4)));
#pragma unroll
      for (int ni = 0; ni < 2; ++ni)
        bfr[ni] = *(const bf16x8*)(Bs + (wc * 32 + ni * 16 + lo) * 256 +
                                   ((kk * 64 + hi * 16) ^ (l7 << 4)));
#pragma unroll
      for (int mi = 0; mi < 4; ++mi)
#pragma unroll
        for (int ni = 0; ni < 2; ++ni)
          acc[mi][ni] =
              __builtin_amdgcn_mfma_f32_16x16x32_bf16(af[mi], bfr[ni], acc[mi][ni], 0, 0, 0);
    }
    __syncthreads();
  }

#pragma unroll
  for (int mi = 0; mi < 4; ++mi)
#pragma unroll
    for (int ni = 0; ni < 2; ++ni) {
      int gcol = n0 + wc * 32 + ni * 16 + lo;
      float bv = bias[gcol];
#pragma unroll
      for (int j = 0; j < 4; ++j) {
        int grow = row0 + wr * 64 + mi * 16 + hi * 4 + j;
        Out[(size_t)grow * 1024 + gcol] = acc[mi][ni][j] + bv;
      }
    }
}

// ---------------- flash attention (32x32 MFMA, sequential-n in-reg softmax) ----------
// (r9 replay-proven form, unchanged)
__global__ __launch_bounds__(512) void attn_kernel(const char* __restrict__ qb,
                                                   const char* __restrict__ kb,
                                                   const char* __restrict__ vb,
                                                   const unsigned long long* __restrict__ mbits,
                                                   bf16* __restrict__ out) {
  __shared__ alignas(16) char smem[32768];
  // [0,16384): Ks [128 kj][8 slots x16B], slot ^= row&7
  // [16384,32768): Vs [64 d][16 slots x16B], slot ^= row&7
  const int t = threadIdx.x;
  const int w = t >> 6, l = t & 63;
  const int q31 = l & 31, hi = l >> 5;
  const int bh = blockIdx.x, b = bh >> 4, h = bh & 15;
  const int q0 = blockIdx.y * 256;
  const int qrow = q0 + w * 32 + q31;

  // Q fragments (B-operand of 32x32x16): col=qi=q31, k = kc*16 + hi*8 + e
  bf16x8 qf[4];
#pragma unroll
  for (int kc = 0; kc < 4; ++kc)
    qf[kc] = *(const bf16x8*)(qb + (size_t)(bh * 2048 + qrow) * 128 + kc * 32 + hi * 16);

  const f32x16 fz16 = {0.f, 0.f, 0.f, 0.f, 0.f, 0.f, 0.f, 0.f,
                       0.f, 0.f, 0.f, 0.f, 0.f, 0.f, 0.f, 0.f};
  f32x16 o[2];  // o[db]: O^T[d = db*32+(r&3)+8*(r>>2)+4*hi][qi=q31]
  o[0] = fz16;
  o[1] = fz16;
  float mreg = -3e38f, ls = 0.f;
  const unsigned long long* mrow = mbits + (size_t)(b * 2048 + qrow) * 32;

  for (int kt2 = 0; kt2 < 16; ++kt2) {
    // stage K[128 kj][64 d] and V^T[64 d][128 kj] (16KB each), swizzled; 2 each/thread
#pragma unroll
    for (int i = 0; i < 2; ++i) {
      int c = i * 512 + t;
      int kr = c >> 3, ks = c & 7;
      gload_lds16(kb + (size_t)(bh * 2048 + kt2 * 128 + kr) * 128 + ((ks ^ (kr & 7)) * 16),
                  smem + (i * 512 + w * 64) * 16);
      int vr = c >> 4, vs = c & 15;
      gload_lds16(vb + (size_t)(bh * 64 + vr) * 4096 + kt2 * 256 + ((vs ^ (vr & 7)) * 16),
                  smem + 16384 + (i * 512 + w * 64) * 16);
    }
    // prefetch this tile's mask words while the barrier drains the staging
    unsigned long long mw01[2] = {mrow[kt2 * 2], mrow[kt2 * 2 + 1]};
    __syncthreads();

#pragma unroll
    for (int h2 = 0; h2 < 2; ++h2) {
      const unsigned long long mw = mw01[h2];

#pragma unroll
      for (int n = 0; n < 2; ++n) {
        // QK^T sub-tile: sc = D[kj = n*32 + crow(r,hi)][qi]
        f32x16 sc = fz16;
        __builtin_amdgcn_s_setprio(1);
#pragma unroll
        for (int kc = 0; kc < 4; ++kc) {
          bf16x8 kf = *(const bf16x8*)(smem + (h2 * 64 + n * 32 + q31) * 128 +
                                       (((kc * 2 + hi) ^ (q31 & 7)) * 16));
          sc = __builtin_amdgcn_mfma_f32_32x32x16_bf16(kf, qf[kc], sc, 0, 0, 0);
        }
        __builtin_amdgcn_s_setprio(0);

        // mask in place + sub-tile max (scores already in log2 domain)
        uint m32 = (uint)(mw >> (n * 32 + 4 * hi));
        float tm = -3e38f;
#pragma unroll
        for (int r = 0; r < 16; ++r) {
          const int bi = (r & 3) + 8 * (r >> 2);
          sc[r] = ((m32 >> bi) & 1u) ? sc[r] : -1e9f;
        }
#pragma unroll
        for (int r = 0; r < 16; r += 2) tm = fmaxf(fmaxf(tm, sc[r]), sc[r + 1]);
        tm = fmaxf(tm, __shfl_xor(tm, 32));

        // defer-max (T13, THR=4): rescale only when sub-tile max grows past mreg+4
        if (!__all(tm - mreg <= 4.f)) {
          float mn = fmaxf(mreg, tm);
          float scal = __builtin_amdgcn_exp2f(mreg - mn);
          ls *= scal;
          o[0] *= scal;
          o[1] *= scal;
          mreg = mn;
        }

        // p = exp2(sc - mreg); pack pairs to bf16x2 words
        uint wpk[8];
#pragma unroll
        for (int r2 = 0; r2 < 8; ++r2) {
          float p0 = __builtin_amdgcn_exp2f(sc[2 * r2] - mreg);
          float p1 = __builtin_amdgcn_exp2f(sc[2 * r2 + 1] - mreg);
          ls += p0 + p1;
          uint pk;
          asm("v_cvt_pk_bf16_f32 %0, %1, %2" : "=v"(pk) : "v"(p0), "v"(p1));
          wpk[r2] = pk;
        }

        // build P fragments via permlane32_swap and run PV for this sub-tile's chunks
        __builtin_amdgcn_s_setprio(1);
#pragma unroll
        for (int c2 = 0; c2 < 2; ++c2) {
          uint a0 = wpk[4 * c2], b0 = wpk[4 * c2 + 2];
          uint a1 = wpk[4 * c2 + 1], b1 = wpk[4 * c2 + 3];
          asm("v_permlane32_swap_b32 %0, %1" : "+v"(a0), "+v"(b0));
          asm("v_permlane32_swap_b32 %0, %1" : "+v"(a1), "+v"(b1));
          union {
            uint u[4];
            bf16x8 v;
          } pf;
          pf.u[0] = a0;
          pf.u[1] = a1;
          pf.u[2] = b0;
          pf.u[3] = b1;
          const int c = n * 2 + c2;  // kj chunk: kj = c*16 + hi*8 + e
          const int slot = (h2 * 8 + c * 2 + hi);
          bf16x8 vf0 = *(const bf16x8*)(smem + 16384 + q31 * 256 +
                                        ((slot ^ (q31 & 7)) * 16));
          bf16x8 vf1 = *(const bf16x8*)(smem + 16384 + (32 + q31) * 256 +
                                        ((slot ^ (q31 & 7)) * 16));
          o[0] = __builtin_amdgcn_mfma_f32_32x32x16_bf16(vf0, pf.v, o[0], 0, 0, 0);
          o[1] = __builtin_amdgcn_mfma_f32_32x32x16_bf16(vf1, pf.v, o[1], 0, 0, 0);
        }
        __builtin_amdgcn_s_setprio(0);
      }
    }
    __syncthreads();
  }

  // epilogue: both hi-halves hold partial ls; combine once
  ls += __shfl_xor(ls, 32);
  float inv = 1.f / ls;
  size_t rbase = (size_t)((b << 11) + qrow) * 1024 + h * 64;
#pragma unroll
  for (int db = 0; db < 2; ++db)
#pragma unroll
    for (int g = 0; g < 4; ++g) {
      bf16x4 hv = {(bf16)(o[db][4 * g] * inv), (bf16)(o[db][4 * g + 1] * inv),
                   (bf16)(o[db][4 * g + 2] * inv), (bf16)(o[db][4 * g + 3] * inv)};
      *(bf16x4*)(out + rbase + db * 32 + 8 * g + 4 * hi) = hv;
    }
}

extern "C" void kernel_launch(void* const* d_in, const int* in_sizes, int n_in,
                              void* d_out, int out_size, void* d_ws, size_t ws_size,
                              hipStream_t stream) {
  const float* query = (const float*)d_in[0];
  const float* key_ = (const float*)d_in[1];
  const float* value = (const float*)d_in[2];
  const int* mask = (const int*)d_in[3];
  const float* Wq = (const float*)d_in[4];
  const float* bq = (const float*)d_in[5];
  const float* Wk = (const float*)d_in[6];
  const float* bk = (const float*)d_in[7];
  const float* Wv = (const float*)d_in[8];
  const float* bv = (const float*)d_in[9];
  const float* Wo = (const float*)d_in[10];
  const float* bo = (const float*)d_in[11];

  char* ws = (char*)d_ws;
  bf16* wt = (bf16*)ws;                      // 4 x 1M bf16
  char* qbuf = ws + 8388608;
  char* kbuf = qbuf + 16777216;
  char* vbuf = kbuf + 16777216;
  char* abuf = vbuf + 16777216;
  unsigned long long* mbits = (unsigned long long*)(abuf + 16777216);

  wt_kernel<<<dim3(16, 16, 4), 256, 0, stream>>>(Wq, Wk, Wv, Wo, wt);
  maskpack_kernel<<<16384, 256, 0, stream>>>(mask, mbits);
  qkv_gemm_kernel<<<dim3(64, 8, 3), 512, 0, stream>>>(query, key_, value, wt, bq, bk, bv,
                                                      qbuf, kbuf, vbuf);
  attn_kernel<<<dim3(64, 8), 512, 0, stream>>>(qbuf, kbuf, vbuf, mbits, (bf16*)abuf);
  gemm3_kernel<<<dim3(64, 8), 512, 0, stream>>>(abuf, wt + 3145728, bo, (float*)d_out);
}